// Round 1
// baseline (22.472 us; speedup 1.0000x reference)
//
#include <hip/hip_runtime.h>
#include <math.h>

// GaussianMixtureLoss: loss = CONST - mean_{b,n}( log sum_m exp(p·g - |g|²/2) - |p|²/2 )
// B=4, N=4096, M=4096, D=3, SIGMA=1.
#define BATCH 4
#define NPTS 4096
#define NMIX 4096
#define NCHUNK 8
#define MCHUNK 512          // NMIX / NCHUNK, one LDS tile per block
#define THREADS 256

#define L2E 1.4426950408889634f
#define LN2 0.6931471805599453f
#define CONST_TERM 0.9189385332046727f  // 0.5*log(2*pi*sigma^2), sigma=1

__device__ __forceinline__ float fast_exp2(float x) {
#if __has_builtin(__builtin_amdgcn_exp2f)
  return __builtin_amdgcn_exp2f(x);   // raw v_exp_f32
#else
  return exp2f(x);
#endif
}
__device__ __forceinline__ float fast_log2(float x) {
#if __has_builtin(__builtin_amdgcn_logf)
  return __builtin_amdgcn_logf(x);    // raw v_log_f32
#else
  return log2f(x);
#endif
}

// Kernel 1: partial sums over an M-chunk for 256 points of one batch.
// partial[gp*NCHUNK + chunk] = sum_{m in chunk} exp2( L2E*(p·g_m - |g_m|²/2) )
__global__ __launch_bounds__(THREADS) void gm_partial(
    const float* __restrict__ pred, const float* __restrict__ gt,
    float* __restrict__ partial) {
  __shared__ float4 gsh[MCHUNK];  // (gx, gy, gz, L2E*|g|²/2) : 8 KB

  const int b = blockIdx.y;
  const int n = blockIdx.x * THREADS + threadIdx.x;
  const int m0 = blockIdx.z * MCHUNK;

  // stage gt chunk into LDS, precompute scaled half-norm
  for (int i = threadIdx.x; i < MCHUNK; i += THREADS) {
    const float* g = gt + ((size_t)(b * NMIX + m0 + i)) * 3;
    float gx = g[0], gy = g[1], gz = g[2];
    gsh[i] = make_float4(gx, gy, gz,
                         0.5f * L2E * (gx * gx + gy * gy + gz * gz));
  }

  const float* p = pred + ((size_t)(b * NPTS + n)) * 3;
  const float pxs = p[0] * L2E, pys = p[1] * L2E, pzs = p[2] * L2E;

  __syncthreads();

  // 4 independent accumulators for ILP; all lanes read same LDS addr (broadcast)
  float s0 = 0.f, s1 = 0.f, s2 = 0.f, s3 = 0.f;
  for (int j = 0; j < MCHUNK; j += 4) {
    float4 a0 = gsh[j + 0];
    float4 a1 = gsh[j + 1];
    float4 a2 = gsh[j + 2];
    float4 a3 = gsh[j + 3];
    s0 += fast_exp2(fmaf(pxs, a0.x, fmaf(pys, a0.y, fmaf(pzs, a0.z, -a0.w))));
    s1 += fast_exp2(fmaf(pxs, a1.x, fmaf(pys, a1.y, fmaf(pzs, a1.z, -a1.w))));
    s2 += fast_exp2(fmaf(pxs, a2.x, fmaf(pys, a2.y, fmaf(pzs, a2.z, -a2.w))));
    s3 += fast_exp2(fmaf(pxs, a3.x, fmaf(pys, a3.y, fmaf(pzs, a3.z, -a3.w))));
  }

  const int gp = b * NPTS + n;
  partial[(size_t)gp * NCHUNK + blockIdx.z] = (s0 + s1) + (s2 + s3);
}

// Kernel 2: per-point combine (plain add across chunks), log, per-block reduce.
__global__ __launch_bounds__(256) void gm_combine(
    const float* __restrict__ pred, const float* __restrict__ partial,
    float* __restrict__ blockpart) {
  const int gp = blockIdx.x * 256 + threadIdx.x;

  const float4* q = (const float4*)(partial + (size_t)gp * NCHUNK);
  float4 q0 = q[0], q1 = q[1];
  float sum = ((q0.x + q0.y) + (q0.z + q0.w)) +
              ((q1.x + q1.y) + (q1.z + q1.w));

  const float* p = pred + (size_t)gp * 3;
  float halfp2 = 0.5f * (p[0] * p[0] + p[1] * p[1] + p[2] * p[2]);

  // ll (sans -CONST) = ln2*log2(sum) - |p|²/2
  float ll = LN2 * fast_log2(sum) - halfp2;

  // block reduce: wave shfl, then 4 wave partials via LDS
  for (int off = 32; off > 0; off >>= 1) ll += __shfl_down(ll, off, 64);
  __shared__ float wsum[4];
  const int wave = threadIdx.x >> 6, lane = threadIdx.x & 63;
  if (lane == 0) wsum[wave] = ll;
  __syncthreads();
  if (threadIdx.x == 0)
    blockpart[blockIdx.x] = (wsum[0] + wsum[1]) + (wsum[2] + wsum[3]);
}

// Kernel 3: final reduce of 64 block partials -> loss scalar.
__global__ __launch_bounds__(64) void gm_final(
    const float* __restrict__ blockpart, float* __restrict__ out) {
  float v = blockpart[threadIdx.x];
  for (int off = 32; off > 0; off >>= 1) v += __shfl_down(v, off, 64);
  if (threadIdx.x == 0)
    out[0] = CONST_TERM - v * (1.0f / (float)(BATCH * NPTS));
}

extern "C" void kernel_launch(void* const* d_in, const int* in_sizes, int n_in,
                              void* d_out, int out_size, void* d_ws, size_t ws_size,
                              hipStream_t stream) {
  const float* pred = (const float*)d_in[0];
  const float* gt   = (const float*)d_in[1];
  float* out = (float*)d_out;

  float* partial   = (float*)d_ws;                            // 16384*8 floats = 512 KB
  float* blockpart = partial + (size_t)BATCH * NPTS * NCHUNK; // +64 floats

  dim3 g1(NPTS / THREADS, BATCH, NCHUNK);  // (16, 4, 8) = 512 blocks
  gm_partial<<<g1, THREADS, 0, stream>>>(pred, gt, partial);

  gm_combine<<<(BATCH * NPTS) / 256, 256, 0, stream>>>(pred, partial, blockpart);

  gm_final<<<1, 64, 0, stream>>>(blockpart, out);
}